// Round 14
// baseline (463.355 us; speedup 1.0000x reference)
//
#include <hip/hip_runtime.h>
#include <hip/hip_fp16.h>

constexpr int N_NODES     = 50000;
constexpr int N_EDGES     = 800000;
constexpr int IN_FEAT     = 96;
constexpr int NUM_CLASSES = 40;
constexpr int CCH = NUM_CLASSES / 4;          // 10 chunks (xw_k)
constexpr int CH8 = NUM_CLASSES / 8;          // 5 chunks of 8 values (walks)
constexpr int HS  = 64;                       // xwt row stride in halves (128 B line)
constexpr int CS  = 128;                      // comb row stride in halves (256 B)
constexpr int LS  = 64;                       // lB row stride in halves (128 B)
constexpr int SCAN_B = 1024;
constexpr int NSCAN = (N_NODES + SCAN_B - 1) / SCAN_B;  // 49 blocks

// ---- fp16 pack/unpack (8 values <-> uint4) ----
__device__ __forceinline__ void h8_to_f(const uint4& u, float4& lo, float4& hi) {
    float2 f0 = __half22float2(*reinterpret_cast<const __half2*>(&u.x));
    float2 f1 = __half22float2(*reinterpret_cast<const __half2*>(&u.y));
    float2 f2 = __half22float2(*reinterpret_cast<const __half2*>(&u.z));
    float2 f3 = __half22float2(*reinterpret_cast<const __half2*>(&u.w));
    lo = make_float4(f0.x, f0.y, f1.x, f1.y);
    hi = make_float4(f2.x, f2.y, f3.x, f3.y);
}
__device__ __forceinline__ uint4 f_to_h8(const float4& lo, const float4& hi) {
    uint4 u;
    *reinterpret_cast<__half2*>(&u.x) = __floats2half2_rn(lo.x, lo.y);
    *reinterpret_cast<__half2*>(&u.y) = __floats2half2_rn(lo.z, lo.w);
    *reinterpret_cast<__half2*>(&u.z) = __floats2half2_rn(hi.x, hi.y);
    *reinterpret_cast<__half2*>(&u.w) = __floats2half2_rn(hi.z, hi.w);
    return u;
}

// ---- pass A: per-edge in-bucket rank + bucket count; 8 edges/thread for ILP ----
__global__ void rank_k(const int* __restrict__ col, int* __restrict__ cnt,
                       int* __restrict__ rank) {
    int t = blockIdx.x * blockDim.x + threadIdx.x;
    if (t >= N_EDGES / 8) return;
    int4 c0 = reinterpret_cast<const int4*>(col)[2 * t];
    int4 c1 = reinterpret_cast<const int4*>(col)[2 * t + 1];
    int4 r0, r1;
    r0.x = atomicAdd(&cnt[c0.x], 1);
    r0.y = atomicAdd(&cnt[c0.y], 1);
    r0.z = atomicAdd(&cnt[c0.z], 1);
    r0.w = atomicAdd(&cnt[c0.w], 1);
    r1.x = atomicAdd(&cnt[c1.x], 1);
    r1.y = atomicAdd(&cnt[c1.y], 1);
    r1.z = atomicAdd(&cnt[c1.z], 1);
    r1.w = atomicAdd(&cnt[c1.w], 1);
    reinterpret_cast<int4*>(rank)[2 * t]     = r0;
    reinterpret_cast<int4*>(rank)[2 * t + 1] = r1;
}

// ---- 3-stage parallel exclusive scan of cnt[0..N_NODES) -> rowptr ----
__global__ __launch_bounds__(SCAN_B) void scan1_k(const int* __restrict__ cnt,
                                                  int* __restrict__ pscan,
                                                  int* __restrict__ bsum) {
    __shared__ int buf[SCAN_B];
    int tid = threadIdx.x;
    int i = blockIdx.x * SCAN_B + tid;
    int v = (i < N_NODES) ? cnt[i] : 0;
    buf[tid] = v;
    __syncthreads();
    for (int off = 1; off < SCAN_B; off <<= 1) {
        int t = (tid >= off) ? buf[tid - off] : 0;
        __syncthreads();
        buf[tid] += t;
        __syncthreads();
    }
    if (i < N_NODES) pscan[i] = buf[tid] - v;        // block-local exclusive
    if (tid == SCAN_B - 1) bsum[blockIdx.x] = buf[tid];
}

__global__ void scan2_k(const int* __restrict__ bsum, int* __restrict__ boff,
                        int* __restrict__ rowptr) {
    __shared__ int buf[64];
    int tid = threadIdx.x;                            // 64 threads
    int v = (tid < NSCAN) ? bsum[tid] : 0;
    buf[tid] = v;
    __syncthreads();
    for (int off = 1; off < 64; off <<= 1) {
        int t = (tid >= off) ? buf[tid - off] : 0;
        __syncthreads();
        buf[tid] += t;
        __syncthreads();
    }
    boff[tid] = buf[tid] - v;                         // exclusive block offsets
    if (tid == NSCAN - 1) rowptr[N_NODES] = buf[tid]; // total == N_EDGES
}

__global__ void scan3_k(const int* __restrict__ pscan, const int* __restrict__ boff,
                        int* __restrict__ rowptr) {
    int i = blockIdx.x * blockDim.x + threadIdx.x;
    if (i < N_NODES) rowptr[i] = boff[i >> 10] + pscan[i];
}

// ---- pass B: CSR fill, atomic-free; 4 edges/thread ----
__global__ void fill_k(const int* __restrict__ row, const int* __restrict__ col,
                       const float* __restrict__ ew, const int* __restrict__ rowptr,
                       const int* __restrict__ rank, int2* __restrict__ pair) {
    int t = blockIdx.x * blockDim.x + threadIdx.x;
    if (t >= N_EDGES / 4) return;
    int4   c = reinterpret_cast<const int4*>(col)[t];
    int4   r = reinterpret_cast<const int4*>(row)[t];
    int4   k = reinterpret_cast<const int4*>(rank)[t];
    float4 w = reinterpret_cast<const float4*>(ew)[t];
    pair[rowptr[c.x] + k.x] = make_int2(r.x, __float_as_int(w.x));
    pair[rowptr[c.y] + k.y] = make_int2(r.y, __float_as_int(w.y));
    pair[rowptr[c.z] + k.z] = make_int2(r.z, __float_as_int(w.z));
    pair[rowptr[c.w] + k.w] = make_int2(r.w, __float_as_int(w.w));
}

// ---- per-node: dinv + masked label embedded in xwt row; degree histogram ----
__global__ void node_prep_k(const int* __restrict__ rowptr, const int2* __restrict__ pair,
                            const int* __restrict__ y, const int* __restrict__ mask,
                            unsigned short* __restrict__ xwt, int* __restrict__ dhist) {
    int i = blockIdx.x * blockDim.x + threadIdx.x;
    if (i >= N_NODES) return;
    int p0 = rowptr[i], p1 = rowptr[i + 1];
    float d = 1.0f;                                   // self-loop weight
    for (int p = p0; p < p1; ++p) d += __int_as_float(pair[p].y);
    float dv = d > 0.0f ? rsqrtf(d) : 0.0f;
    unsigned short* rowp = xwt + (size_t)i * HS;
    *reinterpret_cast<int*>(rowp + 40)   = (mask[i] != 0) ? y[i] : -1;  // bytes 80-84
    *reinterpret_cast<float*>(rowp + 42) = dv;                          // bytes 84-88
    atomicAdd(&dhist[min(p1 - p0, 63)], 1);
}

// ---- 64-bucket exclusive scan -> bucket cursors ----
__global__ void bscan_k(const int* __restrict__ dhist, int* __restrict__ bcur) {
    __shared__ int buf[64];
    int tid = threadIdx.x;                            // 64 threads
    int v = dhist[tid];
    buf[tid] = v;
    __syncthreads();
    for (int off = 1; off < 64; off <<= 1) {
        int t = (tid >= off) ? buf[tid - off] : 0;
        __syncthreads();
        buf[tid] += t;
        __syncthreads();
    }
    bcur[tid] = buf[tid] - v;                         // exclusive
}

// ---- scatter node ids into degree-sorted order ----
__global__ void perm_k(const int* __restrict__ rowptr, int* __restrict__ bcur,
                       int* __restrict__ perm) {
    int i = blockIdx.x * blockDim.x + threadIdx.x;
    if (i >= N_NODES) return;
    int deg = rowptr[i + 1] - rowptr[i];
    int pos = atomicAdd(&bcur[min(deg, 63)], 1);
    perm[pos] = i;
}

// ---- xw = x @ W -> fp16 halves [0,40) of xwt rows ----
__global__ __launch_bounds__(256) void xw_k(const float* __restrict__ x,
                                            const float* __restrict__ Wm,
                                            unsigned short* __restrict__ xwt) {
    __shared__ float4 Ws[IN_FEAT * CCH];              // 96 x 10 float4 = 15 KiB
    int tid = threadIdx.x;
    for (int t = tid; t < IN_FEAT * CCH; t += 256)
        Ws[t] = reinterpret_cast<const float4*>(Wm)[t];
    __syncthreads();
    int idx = blockIdx.x * 256 + tid;
    if (idx >= N_NODES * CCH) return;                 // 500k
    int i = idx / CCH;
    int j = idx - i * CCH;                            // 4-col chunk
    const float4* xr = reinterpret_cast<const float4*>(x + i * IN_FEAT);  // 24 f4
    float4 acc = make_float4(0.f, 0.f, 0.f, 0.f);
#pragma unroll
    for (int f4 = 0; f4 < IN_FEAT / 4; ++f4) {
        float4 xv = xr[f4];
        float4 w0 = Ws[(4 * f4 + 0) * CCH + j];
        float4 w1 = Ws[(4 * f4 + 1) * CCH + j];
        float4 w2 = Ws[(4 * f4 + 2) * CCH + j];
        float4 w3 = Ws[(4 * f4 + 3) * CCH + j];
        acc.x = fmaf(xv.x, w0.x, fmaf(xv.y, w1.x, fmaf(xv.z, w2.x, fmaf(xv.w, w3.x, acc.x))));
        acc.y = fmaf(xv.x, w0.y, fmaf(xv.y, w1.y, fmaf(xv.z, w2.y, fmaf(xv.w, w3.y, acc.y))));
        acc.z = fmaf(xv.x, w0.z, fmaf(xv.y, w1.z, fmaf(xv.z, w2.z, fmaf(xv.w, w3.z, acc.z))));
        acc.w = fmaf(xv.x, w0.w, fmaf(xv.y, w1.w, fmaf(xv.z, w2.w, fmaf(xv.w, w3.w, acc.w))));
    }
    uint2 h;
    *reinterpret_cast<__half2*>(&h.x) = __floats2half2_rn(acc.x, acc.y);
    *reinterpret_cast<__half2*>(&h.y) = __floats2half2_rn(acc.z, acc.w);
    reinterpret_cast<uint2*>(xwt + (size_t)i * HS)[j] = h;
}

// ---- K1: fused SGC hop1 + LPA iter1; degree-sorted node order ----
__global__ void fused1_k(const int* __restrict__ rowptr, const int2* __restrict__ pair,
                         const int* __restrict__ perm,
                         const unsigned short* __restrict__ xwt,
                         unsigned short* __restrict__ comb) {
    int idx = blockIdx.x * blockDim.x + threadIdx.x;
    if (idx >= N_NODES * CH8) return;                 // 250k
    int i = perm[idx / CH8];                          // degree-sorted
    int j = idx % CH8;                                // 8-col chunk
    int p0 = rowptr[i], p1 = rowptr[i + 1];
    const unsigned short* irow = xwt + (size_t)i * HS;
    float dc = *reinterpret_cast<const float*>(irow + 42);
    float selfw = dc * dc;
    uint4 vh = *reinterpret_cast<const uint4*>(irow + j * 8);
    float4 v0, v1; h8_to_f(vh, v0, v1);
    float4 s0 = make_float4(selfw * v0.x, selfw * v0.y, selfw * v0.z, selfw * v0.w);
    float4 s1 = make_float4(selfw * v1.x, selfw * v1.y, selfw * v1.z, selfw * v1.w);
    float4 a0 = make_float4(0.f, 0.f, 0.f, 0.f);
    float4 a1 = make_float4(0.f, 0.f, 0.f, 0.f);
    int base = j << 3;
    for (int p = p0; p < p1; ++p) {
        int2 pr = pair[p];
        int s = pr.x;
        float w = __int_as_float(pr.y);
        const unsigned short* srow = xwt + (size_t)s * HS;
        uint4 uh = *reinterpret_cast<const uint4*>(srow + j * 8);
        int   t  = *reinterpret_cast<const int*>(srow + 40) - base;
        float ds = *reinterpret_cast<const float*>(srow + 42);
        float nv = ds * (w * dc);                     // gcn norm on the fly
        float4 u0, u1; h8_to_f(uh, u0, u1);
        s0.x = fmaf(nv, u0.x, s0.x); s0.y = fmaf(nv, u0.y, s0.y);
        s0.z = fmaf(nv, u0.z, s0.z); s0.w = fmaf(nv, u0.w, s0.w);
        s1.x = fmaf(nv, u1.x, s1.x); s1.y = fmaf(nv, u1.y, s1.y);
        s1.z = fmaf(nv, u1.z, s1.z); s1.w = fmaf(nv, u1.w, s1.w);
        a0.x += (t == 0) ? w : 0.f; a0.y += (t == 1) ? w : 0.f;
        a0.z += (t == 2) ? w : 0.f; a0.w += (t == 3) ? w : 0.f;
        a1.x += (t == 4) ? w : 0.f; a1.y += (t == 5) ? w : 0.f;
        a1.z += (t == 6) ? w : 0.f; a1.w += (t == 7) ? w : 0.f;
    }
    unsigned short* crow = comb + (size_t)i * CS;
    *reinterpret_cast<uint4*>(crow + j * 8)      = f_to_h8(s0, s1);  // g1 halves [0,40)
    *reinterpret_cast<uint4*>(crow + 40 + j * 8) = f_to_h8(a0, a1);  // lA halves [40,80)
    if (j == 0) *reinterpret_cast<float*>(crow + 80) = dc;           // dinv bytes 160-164
}

// ---- K2: fused SGC hop2 (+bias -> out f32) + LPA iter2; degree-sorted ----
__global__ void fused2_k(const int* __restrict__ rowptr, const int2* __restrict__ pair,
                         const int* __restrict__ perm,
                         const unsigned short* __restrict__ comb,
                         const float* __restrict__ bias,
                         float* __restrict__ out, unsigned short* __restrict__ lBh) {
    int idx = blockIdx.x * blockDim.x + threadIdx.x;
    if (idx >= N_NODES * CH8) return;                 // 250k
    int i = perm[idx / CH8];
    int j = idx % CH8;
    int p0 = rowptr[i], p1 = rowptr[i + 1];
    const unsigned short* irow = comb + (size_t)i * CS;
    float dc = *reinterpret_cast<const float*>(irow + 80);
    float selfw = dc * dc;
    uint4 vh = *reinterpret_cast<const uint4*>(irow + j * 8);
    float4 v0, v1; h8_to_f(vh, v0, v1);
    float4 s0 = make_float4(selfw * v0.x, selfw * v0.y, selfw * v0.z, selfw * v0.w);
    float4 s1 = make_float4(selfw * v1.x, selfw * v1.y, selfw * v1.z, selfw * v1.w);
    float4 a0 = make_float4(0.f, 0.f, 0.f, 0.f);
    float4 a1 = make_float4(0.f, 0.f, 0.f, 0.f);
    for (int p = p0; p < p1; ++p) {
        int2 pr = pair[p];
        int s = pr.x;
        float w = __int_as_float(pr.y);
        const unsigned short* srow = comb + (size_t)s * CS;
        uint4 uh = *reinterpret_cast<const uint4*>(srow + j * 8);
        uint4 mh = *reinterpret_cast<const uint4*>(srow + 40 + j * 8);
        float ds = *reinterpret_cast<const float*>(srow + 80);
        float nv = ds * (w * dc);
        float4 u0, u1; h8_to_f(uh, u0, u1);
        float4 m0, m1; h8_to_f(mh, m0, m1);
        s0.x = fmaf(nv, u0.x, s0.x); s0.y = fmaf(nv, u0.y, s0.y);
        s0.z = fmaf(nv, u0.z, s0.z); s0.w = fmaf(nv, u0.w, s0.w);
        s1.x = fmaf(nv, u1.x, s1.x); s1.y = fmaf(nv, u1.y, s1.y);
        s1.z = fmaf(nv, u1.z, s1.z); s1.w = fmaf(nv, u1.w, s1.w);
        a0.x = fmaf(w, m0.x, a0.x); a0.y = fmaf(w, m0.y, a0.y);
        a0.z = fmaf(w, m0.z, a0.z); a0.w = fmaf(w, m0.w, a0.w);
        a1.x = fmaf(w, m1.x, a1.x); a1.y = fmaf(w, m1.y, a1.y);
        a1.z = fmaf(w, m1.z, a1.z); a1.w = fmaf(w, m1.w, a1.w);
    }
    const float4* br = reinterpret_cast<const float4*>(bias) + 2 * j;
    float4 b0 = br[0], b1 = br[1];
    s0.x += b0.x; s0.y += b0.y; s0.z += b0.z; s0.w += b0.w;
    s1.x += b1.x; s1.y += b1.y; s1.z += b1.z; s1.w += b1.w;
    float4* oo = reinterpret_cast<float4*>(out + (size_t)i * NUM_CLASSES) + 2 * j;
    oo[0] = s0; oo[1] = s1;                           // final SGC output: f32
    *reinterpret_cast<uint4*>(lBh + (size_t)i * LS + j * 8) = f_to_h8(a0, a1);
}

// ---- K3: LPA iter3 (lBh -> lpa_out f32); degree-sorted ----
__global__ void lpa3_k(const int* __restrict__ rowptr, const int2* __restrict__ pair,
                       const int* __restrict__ perm,
                       const unsigned short* __restrict__ lBh, float* __restrict__ lout) {
    int idx = blockIdx.x * blockDim.x + threadIdx.x;
    if (idx >= N_NODES * CH8) return;                 // 250k
    int i = perm[idx / CH8];
    int j = idx % CH8;
    int p0 = rowptr[i], p1 = rowptr[i + 1];
    float4 a0 = make_float4(0.f, 0.f, 0.f, 0.f);
    float4 a1 = make_float4(0.f, 0.f, 0.f, 0.f);
    for (int p = p0; p < p1; ++p) {
        int2 pr = pair[p];
        int s = pr.x;
        float w = __int_as_float(pr.y);
        uint4 mh = *reinterpret_cast<const uint4*>(lBh + (size_t)s * LS + j * 8);
        float4 m0, m1; h8_to_f(mh, m0, m1);
        a0.x = fmaf(w, m0.x, a0.x); a0.y = fmaf(w, m0.y, a0.y);
        a0.z = fmaf(w, m0.z, a0.z); a0.w = fmaf(w, m0.w, a0.w);
        a1.x = fmaf(w, m1.x, a1.x); a1.y = fmaf(w, m1.y, a1.y);
        a1.z = fmaf(w, m1.z, a1.z); a1.w = fmaf(w, m1.w, a1.w);
    }
    float4* lo = reinterpret_cast<float4*>(lout + (size_t)i * NUM_CLASSES) + 2 * j;
    lo[0] = a0; lo[1] = a1;                           // final LPA output: f32
}

// ---------------- launch ----------------

extern "C" void kernel_launch(void* const* d_in, const int* in_sizes, int n_in,
                              void* d_out, int out_size, void* d_ws, size_t ws_size,
                              hipStream_t stream) {
    const float* x    = (const float*)d_in[0];
    const int*   ei   = (const int*)d_in[1];
    const int*   row  = ei;
    const int*   col  = ei + N_EDGES;
    const int*   y    = (const int*)d_in[2];
    const int*   mask = (const int*)d_in[3];
    const float* ew   = (const float*)d_in[4];
    const float* Wm   = (const float*)d_in[5];
    const float* bias = (const float*)d_in[6];
    float* out     = (float*)d_out;
    float* lpa_out = out + N_NODES * NUM_CLASSES;

    // workspace layout: big aligned tables first
    unsigned short* xwt  = (unsigned short*)d_ws;               // 50000*64 u16 = 6.4 MB
    unsigned short* comb = xwt + (size_t)N_NODES * HS;          // 50000*128 u16 = 12.8 MB
    unsigned short* lBh  = comb + (size_t)N_NODES * CS;         // 50000*64 u16 = 6.4 MB
    int2* pair  = (int2*)(lBh + (size_t)N_NODES * LS);          // 800000 int2 = 6.4 MB
    int* wsi    = (int*)(pair + N_EDGES);
    int* cnt    = wsi;                                          // 50000
    int* dhist  = cnt + 50000;                                  // 64
    int* bcur   = dhist + 64;                                   // 64
    int* pscan  = bcur + 64;                                    // 50048
    int* bsum   = pscan + 50048;                                // 64
    int* boff   = bsum + 64;                                    // 64
    int* rowptr = boff + 64;                                    // 50004
    int* rank   = rowptr + 50004;                               // 800000
    int* perm   = rank + 800000;                                // 50000

    const int B = 256;
    auto g = [](long long n, int b) { return (int)((n + b - 1) / b); };

    // ---- CSR build: rank pass (only atomic pass) -> scan -> atomic-free fill ----
    hipMemsetAsync(cnt, 0, (50000u + 128u) * sizeof(int), stream);  // cnt + dhist + bcur
    rank_k<<<g(N_EDGES / 8, B), B, 0, stream>>>(col, cnt, rank);
    scan1_k<<<NSCAN, SCAN_B, 0, stream>>>(cnt, pscan, bsum);
    scan2_k<<<1, 64, 0, stream>>>(bsum, boff, rowptr);
    scan3_k<<<g(N_NODES, B), B, 0, stream>>>(pscan, boff, rowptr);
    fill_k<<<g(N_EDGES / 4, B), B, 0, stream>>>(row, col, ew, rowptr, rank, pair);

    // ---- per-node prep (dinv, label, degree histogram) + degree-sort permutation ----
    node_prep_k<<<g(N_NODES, B), B, 0, stream>>>(rowptr, pair, y, mask, xwt, dhist);
    bscan_k<<<1, 64, 0, stream>>>(dhist, bcur);
    perm_k<<<g(N_NODES, B), B, 0, stream>>>(rowptr, bcur, perm);

    // ---- project first: xwt[:, 0:40) = fp16(x @ W) ----
    xw_k<<<g((long long)N_NODES * CCH, B), B, 0, stream>>>(x, Wm, xwt);

    // ---- fused propagation: 3 CSR walks, degree-sorted node order ----
    fused1_k<<<g((long long)N_NODES * CH8, B), B, 0, stream>>>(
        rowptr, pair, perm, xwt, comb);
    fused2_k<<<g((long long)N_NODES * CH8, B), B, 0, stream>>>(
        rowptr, pair, perm, comb, bias, out, lBh);
    lpa3_k<<<g((long long)N_NODES * CH8, B), B, 0, stream>>>(
        rowptr, pair, perm, lBh, lpa_out);
}

// Round 15
// 255.705 us; speedup vs baseline: 1.8121x; 1.8121x over previous
//
#include <hip/hip_runtime.h>
#include <hip/hip_fp16.h>

constexpr int N_NODES     = 50000;
constexpr int N_EDGES     = 800000;
constexpr int IN_FEAT     = 96;
constexpr int NUM_CLASSES = 40;
constexpr int CCH = NUM_CLASSES / 4;          // 10 chunks (xw_k)
constexpr int CH8 = NUM_CLASSES / 8;          // 5 chunks of 8 values (walks)
constexpr int HS  = 64;                       // xwt row stride in halves (128 B line)
constexpr int CS  = 128;                      // comb row stride in halves (256 B)
constexpr int LS  = 64;                       // lB row stride in halves (128 B)
constexpr int SCAN_B = 1024;
constexpr int NSCAN = (N_NODES + SCAN_B - 1) / SCAN_B;  // 49 blocks

// ---- fp16 pack/unpack (8 values <-> uint4) ----
__device__ __forceinline__ void h8_to_f(const uint4& u, float4& lo, float4& hi) {
    float2 f0 = __half22float2(*reinterpret_cast<const __half2*>(&u.x));
    float2 f1 = __half22float2(*reinterpret_cast<const __half2*>(&u.y));
    float2 f2 = __half22float2(*reinterpret_cast<const __half2*>(&u.z));
    float2 f3 = __half22float2(*reinterpret_cast<const __half2*>(&u.w));
    lo = make_float4(f0.x, f0.y, f1.x, f1.y);
    hi = make_float4(f2.x, f2.y, f3.x, f3.y);
}
__device__ __forceinline__ uint4 f_to_h8(const float4& lo, const float4& hi) {
    uint4 u;
    *reinterpret_cast<__half2*>(&u.x) = __floats2half2_rn(lo.x, lo.y);
    *reinterpret_cast<__half2*>(&u.y) = __floats2half2_rn(lo.z, lo.w);
    *reinterpret_cast<__half2*>(&u.z) = __floats2half2_rn(hi.x, hi.y);
    *reinterpret_cast<__half2*>(&u.w) = __floats2half2_rn(hi.z, hi.w);
    return u;
}

// ---- pass A: per-edge in-bucket rank + bucket count; 8 edges/thread for ILP ----
__global__ void rank_k(const int* __restrict__ col, int* __restrict__ cnt,
                       int* __restrict__ rank) {
    int t = blockIdx.x * blockDim.x + threadIdx.x;
    if (t >= N_EDGES / 8) return;
    int4 c0 = reinterpret_cast<const int4*>(col)[2 * t];
    int4 c1 = reinterpret_cast<const int4*>(col)[2 * t + 1];
    int4 r0, r1;
    r0.x = atomicAdd(&cnt[c0.x], 1);
    r0.y = atomicAdd(&cnt[c0.y], 1);
    r0.z = atomicAdd(&cnt[c0.z], 1);
    r0.w = atomicAdd(&cnt[c0.w], 1);
    r1.x = atomicAdd(&cnt[c1.x], 1);
    r1.y = atomicAdd(&cnt[c1.y], 1);
    r1.z = atomicAdd(&cnt[c1.z], 1);
    r1.w = atomicAdd(&cnt[c1.w], 1);
    reinterpret_cast<int4*>(rank)[2 * t]     = r0;
    reinterpret_cast<int4*>(rank)[2 * t + 1] = r1;
}

// ---- 3-stage parallel exclusive scan of cnt[0..N_NODES) -> rowptr ----
__global__ __launch_bounds__(SCAN_B) void scan1_k(const int* __restrict__ cnt,
                                                  int* __restrict__ pscan,
                                                  int* __restrict__ bsum) {
    __shared__ int buf[SCAN_B];
    int tid = threadIdx.x;
    int i = blockIdx.x * SCAN_B + tid;
    int v = (i < N_NODES) ? cnt[i] : 0;
    buf[tid] = v;
    __syncthreads();
    for (int off = 1; off < SCAN_B; off <<= 1) {
        int t = (tid >= off) ? buf[tid - off] : 0;
        __syncthreads();
        buf[tid] += t;
        __syncthreads();
    }
    if (i < N_NODES) pscan[i] = buf[tid] - v;        // block-local exclusive
    if (tid == SCAN_B - 1) bsum[blockIdx.x] = buf[tid];
}

__global__ void scan2_k(const int* __restrict__ bsum, int* __restrict__ boff,
                        int* __restrict__ rowptr) {
    __shared__ int buf[64];
    int tid = threadIdx.x;                            // 64 threads
    int v = (tid < NSCAN) ? bsum[tid] : 0;
    buf[tid] = v;
    __syncthreads();
    for (int off = 1; off < 64; off <<= 1) {
        int t = (tid >= off) ? buf[tid - off] : 0;
        __syncthreads();
        buf[tid] += t;
        __syncthreads();
    }
    boff[tid] = buf[tid] - v;                         // exclusive block offsets
    if (tid == NSCAN - 1) rowptr[N_NODES] = buf[tid]; // total == N_EDGES
}

__global__ void scan3_k(const int* __restrict__ pscan, const int* __restrict__ boff,
                        int* __restrict__ rowptr) {
    int i = blockIdx.x * blockDim.x + threadIdx.x;
    if (i < N_NODES) rowptr[i] = boff[i >> 10] + pscan[i];
}

// ---- pass B: CSR fill, atomic-free; 4 edges/thread ----
__global__ void fill_k(const int* __restrict__ row, const int* __restrict__ col,
                       const float* __restrict__ ew, const int* __restrict__ rowptr,
                       const int* __restrict__ rank, int2* __restrict__ pair) {
    int t = blockIdx.x * blockDim.x + threadIdx.x;
    if (t >= N_EDGES / 4) return;
    int4   c = reinterpret_cast<const int4*>(col)[t];
    int4   r = reinterpret_cast<const int4*>(row)[t];
    int4   k = reinterpret_cast<const int4*>(rank)[t];
    float4 w = reinterpret_cast<const float4*>(ew)[t];
    pair[rowptr[c.x] + k.x] = make_int2(r.x, __float_as_int(w.x));
    pair[rowptr[c.y] + k.y] = make_int2(r.y, __float_as_int(w.y));
    pair[rowptr[c.z] + k.z] = make_int2(r.z, __float_as_int(w.z));
    pair[rowptr[c.w] + k.w] = make_int2(r.w, __float_as_int(w.w));
}

// ---- per-node: dinv + masked label into xwt row; LDS-aggregated degree histogram ----
__global__ __launch_bounds__(256) void node_prep_k(
        const int* __restrict__ rowptr, const int2* __restrict__ pair,
        const int* __restrict__ y, const int* __restrict__ mask,
        unsigned short* __restrict__ xwt, int* __restrict__ dhist) {
    __shared__ int lh[64];
    int tid = threadIdx.x;
    if (tid < 64) lh[tid] = 0;
    __syncthreads();
    int i = blockIdx.x * 256 + tid;
    if (i < N_NODES) {
        int p0 = rowptr[i], p1 = rowptr[i + 1];
        float d = 1.0f;                               // self-loop weight
        for (int p = p0; p < p1; ++p) d += __int_as_float(pair[p].y);
        float dv = d > 0.0f ? rsqrtf(d) : 0.0f;
        unsigned short* rowp = xwt + (size_t)i * HS;
        *reinterpret_cast<int*>(rowp + 40)   = (mask[i] != 0) ? y[i] : -1; // bytes 80-84
        *reinterpret_cast<float*>(rowp + 42) = dv;                         // bytes 84-88
        atomicAdd(&lh[min(p1 - p0, 63)], 1);          // LDS atomic: cheap
    }
    __syncthreads();
    if (tid < 64 && lh[tid] != 0) atomicAdd(&dhist[tid], lh[tid]);
}

// ---- 64-bucket exclusive scan -> bucket cursors ----
__global__ void bscan_k(const int* __restrict__ dhist, int* __restrict__ bcur) {
    __shared__ int buf[64];
    int tid = threadIdx.x;                            // 64 threads
    int v = dhist[tid];
    buf[tid] = v;
    __syncthreads();
    for (int off = 1; off < 64; off <<= 1) {
        int t = (tid >= off) ? buf[tid - off] : 0;
        __syncthreads();
        buf[tid] += t;
        __syncthreads();
    }
    bcur[tid] = buf[tid] - v;                         // exclusive
}

// ---- scatter node ids into degree-sorted order; LDS-aggregated ranks ----
__global__ __launch_bounds__(256) void perm_k(const int* __restrict__ rowptr,
                                              int* __restrict__ bcur,
                                              int* __restrict__ perm) {
    __shared__ int lcnt[64];
    __shared__ int lbase[64];
    int tid = threadIdx.x;
    if (tid < 64) lcnt[tid] = 0;
    __syncthreads();
    int i = blockIdx.x * 256 + tid;
    int b = 0, lr = 0;
    bool act = (i < N_NODES);
    if (act) {
        int deg = rowptr[i + 1] - rowptr[i];
        b = min(deg, 63);
        lr = atomicAdd(&lcnt[b], 1);                  // LDS: local rank
    }
    __syncthreads();
    if (tid < 64 && lcnt[tid] != 0)
        lbase[tid] = atomicAdd(&bcur[tid], lcnt[tid]); // 1 global atomic / bucket / block
    __syncthreads();
    if (act) perm[lbase[b] + lr] = i;
}

// ---- xw = x @ W -> fp16 halves [0,40) of xwt rows ----
__global__ __launch_bounds__(256) void xw_k(const float* __restrict__ x,
                                            const float* __restrict__ Wm,
                                            unsigned short* __restrict__ xwt) {
    __shared__ float4 Ws[IN_FEAT * CCH];              // 96 x 10 float4 = 15 KiB
    int tid = threadIdx.x;
    for (int t = tid; t < IN_FEAT * CCH; t += 256)
        Ws[t] = reinterpret_cast<const float4*>(Wm)[t];
    __syncthreads();
    int idx = blockIdx.x * 256 + tid;
    if (idx >= N_NODES * CCH) return;                 // 500k
    int i = idx / CCH;
    int j = idx - i * CCH;                            // 4-col chunk
    const float4* xr = reinterpret_cast<const float4*>(x + i * IN_FEAT);  // 24 f4
    float4 acc = make_float4(0.f, 0.f, 0.f, 0.f);
#pragma unroll
    for (int f4 = 0; f4 < IN_FEAT / 4; ++f4) {
        float4 xv = xr[f4];
        float4 w0 = Ws[(4 * f4 + 0) * CCH + j];
        float4 w1 = Ws[(4 * f4 + 1) * CCH + j];
        float4 w2 = Ws[(4 * f4 + 2) * CCH + j];
        float4 w3 = Ws[(4 * f4 + 3) * CCH + j];
        acc.x = fmaf(xv.x, w0.x, fmaf(xv.y, w1.x, fmaf(xv.z, w2.x, fmaf(xv.w, w3.x, acc.x))));
        acc.y = fmaf(xv.x, w0.y, fmaf(xv.y, w1.y, fmaf(xv.z, w2.y, fmaf(xv.w, w3.y, acc.y))));
        acc.z = fmaf(xv.x, w0.z, fmaf(xv.y, w1.z, fmaf(xv.z, w2.z, fmaf(xv.w, w3.z, acc.z))));
        acc.w = fmaf(xv.x, w0.w, fmaf(xv.y, w1.w, fmaf(xv.z, w2.w, fmaf(xv.w, w3.w, acc.w))));
    }
    uint2 h;
    *reinterpret_cast<__half2*>(&h.x) = __floats2half2_rn(acc.x, acc.y);
    *reinterpret_cast<__half2*>(&h.y) = __floats2half2_rn(acc.z, acc.w);
    reinterpret_cast<uint2*>(xwt + (size_t)i * HS)[j] = h;
}

// ---- K1: fused SGC hop1 + LPA iter1; degree-sorted node order ----
__global__ void fused1_k(const int* __restrict__ rowptr, const int2* __restrict__ pair,
                         const int* __restrict__ perm,
                         const unsigned short* __restrict__ xwt,
                         unsigned short* __restrict__ comb) {
    int idx = blockIdx.x * blockDim.x + threadIdx.x;
    if (idx >= N_NODES * CH8) return;                 // 250k
    int i = perm[idx / CH8];                          // degree-sorted
    int j = idx % CH8;                                // 8-col chunk
    int p0 = rowptr[i], p1 = rowptr[i + 1];
    const unsigned short* irow = xwt + (size_t)i * HS;
    float dc = *reinterpret_cast<const float*>(irow + 42);
    float selfw = dc * dc;
    uint4 vh = *reinterpret_cast<const uint4*>(irow + j * 8);
    float4 v0, v1; h8_to_f(vh, v0, v1);
    float4 s0 = make_float4(selfw * v0.x, selfw * v0.y, selfw * v0.z, selfw * v0.w);
    float4 s1 = make_float4(selfw * v1.x, selfw * v1.y, selfw * v1.z, selfw * v1.w);
    float4 a0 = make_float4(0.f, 0.f, 0.f, 0.f);
    float4 a1 = make_float4(0.f, 0.f, 0.f, 0.f);
    int base = j << 3;
    for (int p = p0; p < p1; ++p) {
        int2 pr = pair[p];
        int s = pr.x;
        float w = __int_as_float(pr.y);
        const unsigned short* srow = xwt + (size_t)s * HS;
        uint4 uh = *reinterpret_cast<const uint4*>(srow + j * 8);
        int   t  = *reinterpret_cast<const int*>(srow + 40) - base;
        float ds = *reinterpret_cast<const float*>(srow + 42);
        float nv = ds * (w * dc);                     // gcn norm on the fly
        float4 u0, u1; h8_to_f(uh, u0, u1);
        s0.x = fmaf(nv, u0.x, s0.x); s0.y = fmaf(nv, u0.y, s0.y);
        s0.z = fmaf(nv, u0.z, s0.z); s0.w = fmaf(nv, u0.w, s0.w);
        s1.x = fmaf(nv, u1.x, s1.x); s1.y = fmaf(nv, u1.y, s1.y);
        s1.z = fmaf(nv, u1.z, s1.z); s1.w = fmaf(nv, u1.w, s1.w);
        a0.x += (t == 0) ? w : 0.f; a0.y += (t == 1) ? w : 0.f;
        a0.z += (t == 2) ? w : 0.f; a0.w += (t == 3) ? w : 0.f;
        a1.x += (t == 4) ? w : 0.f; a1.y += (t == 5) ? w : 0.f;
        a1.z += (t == 6) ? w : 0.f; a1.w += (t == 7) ? w : 0.f;
    }
    unsigned short* crow = comb + (size_t)i * CS;
    *reinterpret_cast<uint4*>(crow + j * 8)      = f_to_h8(s0, s1);  // g1 halves [0,40)
    *reinterpret_cast<uint4*>(crow + 40 + j * 8) = f_to_h8(a0, a1);  // lA halves [40,80)
    if (j == 0) *reinterpret_cast<float*>(crow + 80) = dc;           // dinv bytes 160-164
}

// ---- K2: fused SGC hop2 (+bias -> out f32) + LPA iter2; degree-sorted ----
__global__ void fused2_k(const int* __restrict__ rowptr, const int2* __restrict__ pair,
                         const int* __restrict__ perm,
                         const unsigned short* __restrict__ comb,
                         const float* __restrict__ bias,
                         float* __restrict__ out, unsigned short* __restrict__ lBh) {
    int idx = blockIdx.x * blockDim.x + threadIdx.x;
    if (idx >= N_NODES * CH8) return;                 // 250k
    int i = perm[idx / CH8];
    int j = idx % CH8;
    int p0 = rowptr[i], p1 = rowptr[i + 1];
    const unsigned short* irow = comb + (size_t)i * CS;
    float dc = *reinterpret_cast<const float*>(irow + 80);
    float selfw = dc * dc;
    uint4 vh = *reinterpret_cast<const uint4*>(irow + j * 8);
    float4 v0, v1; h8_to_f(vh, v0, v1);
    float4 s0 = make_float4(selfw * v0.x, selfw * v0.y, selfw * v0.z, selfw * v0.w);
    float4 s1 = make_float4(selfw * v1.x, selfw * v1.y, selfw * v1.z, selfw * v1.w);
    float4 a0 = make_float4(0.f, 0.f, 0.f, 0.f);
    float4 a1 = make_float4(0.f, 0.f, 0.f, 0.f);
    for (int p = p0; p < p1; ++p) {
        int2 pr = pair[p];
        int s = pr.x;
        float w = __int_as_float(pr.y);
        const unsigned short* srow = comb + (size_t)s * CS;
        uint4 uh = *reinterpret_cast<const uint4*>(srow + j * 8);
        uint4 mh = *reinterpret_cast<const uint4*>(srow + 40 + j * 8);
        float ds = *reinterpret_cast<const float*>(srow + 80);
        float nv = ds * (w * dc);
        float4 u0, u1; h8_to_f(uh, u0, u1);
        float4 m0, m1; h8_to_f(mh, m0, m1);
        s0.x = fmaf(nv, u0.x, s0.x); s0.y = fmaf(nv, u0.y, s0.y);
        s0.z = fmaf(nv, u0.z, s0.z); s0.w = fmaf(nv, u0.w, s0.w);
        s1.x = fmaf(nv, u1.x, s1.x); s1.y = fmaf(nv, u1.y, s1.y);
        s1.z = fmaf(nv, u1.z, s1.z); s1.w = fmaf(nv, u1.w, s1.w);
        a0.x = fmaf(w, m0.x, a0.x); a0.y = fmaf(w, m0.y, a0.y);
        a0.z = fmaf(w, m0.z, a0.z); a0.w = fmaf(w, m0.w, a0.w);
        a1.x = fmaf(w, m1.x, a1.x); a1.y = fmaf(w, m1.y, a1.y);
        a1.z = fmaf(w, m1.z, a1.z); a1.w = fmaf(w, m1.w, a1.w);
    }
    const float4* br = reinterpret_cast<const float4*>(bias) + 2 * j;
    float4 b0 = br[0], b1 = br[1];
    s0.x += b0.x; s0.y += b0.y; s0.z += b0.z; s0.w += b0.w;
    s1.x += b1.x; s1.y += b1.y; s1.z += b1.z; s1.w += b1.w;
    float4* oo = reinterpret_cast<float4*>(out + (size_t)i * NUM_CLASSES) + 2 * j;
    oo[0] = s0; oo[1] = s1;                           // final SGC output: f32
    *reinterpret_cast<uint4*>(lBh + (size_t)i * LS + j * 8) = f_to_h8(a0, a1);
}

// ---- K3: LPA iter3 (lBh -> lpa_out f32); degree-sorted ----
__global__ void lpa3_k(const int* __restrict__ rowptr, const int2* __restrict__ pair,
                       const int* __restrict__ perm,
                       const unsigned short* __restrict__ lBh, float* __restrict__ lout) {
    int idx = blockIdx.x * blockDim.x + threadIdx.x;
    if (idx >= N_NODES * CH8) return;                 // 250k
    int i = perm[idx / CH8];
    int j = idx % CH8;
    int p0 = rowptr[i], p1 = rowptr[i + 1];
    float4 a0 = make_float4(0.f, 0.f, 0.f, 0.f);
    float4 a1 = make_float4(0.f, 0.f, 0.f, 0.f);
    for (int p = p0; p < p1; ++p) {
        int2 pr = pair[p];
        int s = pr.x;
        float w = __int_as_float(pr.y);
        uint4 mh = *reinterpret_cast<const uint4*>(lBh + (size_t)s * LS + j * 8);
        float4 m0, m1; h8_to_f(mh, m0, m1);
        a0.x = fmaf(w, m0.x, a0.x); a0.y = fmaf(w, m0.y, a0.y);
        a0.z = fmaf(w, m0.z, a0.z); a0.w = fmaf(w, m0.w, a0.w);
        a1.x = fmaf(w, m1.x, a1.x); a1.y = fmaf(w, m1.y, a1.y);
        a1.z = fmaf(w, m1.z, a1.z); a1.w = fmaf(w, m1.w, a1.w);
    }
    float4* lo = reinterpret_cast<float4*>(lout + (size_t)i * NUM_CLASSES) + 2 * j;
    lo[0] = a0; lo[1] = a1;                           // final LPA output: f32
}

// ---------------- launch ----------------

extern "C" void kernel_launch(void* const* d_in, const int* in_sizes, int n_in,
                              void* d_out, int out_size, void* d_ws, size_t ws_size,
                              hipStream_t stream) {
    const float* x    = (const float*)d_in[0];
    const int*   ei   = (const int*)d_in[1];
    const int*   row  = ei;
    const int*   col  = ei + N_EDGES;
    const int*   y    = (const int*)d_in[2];
    const int*   mask = (const int*)d_in[3];
    const float* ew   = (const float*)d_in[4];
    const float* Wm   = (const float*)d_in[5];
    const float* bias = (const float*)d_in[6];
    float* out     = (float*)d_out;
    float* lpa_out = out + N_NODES * NUM_CLASSES;

    // workspace layout: big aligned tables first
    unsigned short* xwt  = (unsigned short*)d_ws;               // 50000*64 u16 = 6.4 MB
    unsigned short* comb = xwt + (size_t)N_NODES * HS;          // 50000*128 u16 = 12.8 MB
    unsigned short* lBh  = comb + (size_t)N_NODES * CS;         // 50000*64 u16 = 6.4 MB
    int2* pair  = (int2*)(lBh + (size_t)N_NODES * LS);          // 800000 int2 = 6.4 MB
    int* wsi    = (int*)(pair + N_EDGES);
    int* cnt    = wsi;                                          // 50000
    int* dhist  = cnt + 50000;                                  // 64
    int* bcur   = dhist + 64;                                   // 64
    int* pscan  = bcur + 64;                                    // 50048
    int* bsum   = pscan + 50048;                                // 64
    int* boff   = bsum + 64;                                    // 64
    int* rowptr = boff + 64;                                    // 50004
    int* rank   = rowptr + 50004;                               // 800000
    int* perm   = rank + 800000;                                // 50000

    const int B = 256;
    auto g = [](long long n, int b) { return (int)((n + b - 1) / b); };

    // ---- CSR build: rank pass (only atomic pass) -> scan -> atomic-free fill ----
    hipMemsetAsync(cnt, 0, (50000u + 128u) * sizeof(int), stream);  // cnt + dhist + bcur
    rank_k<<<g(N_EDGES / 8, B), B, 0, stream>>>(col, cnt, rank);
    scan1_k<<<NSCAN, SCAN_B, 0, stream>>>(cnt, pscan, bsum);
    scan2_k<<<1, 64, 0, stream>>>(bsum, boff, rowptr);
    scan3_k<<<g(N_NODES, B), B, 0, stream>>>(pscan, boff, rowptr);
    fill_k<<<g(N_EDGES / 4, B), B, 0, stream>>>(row, col, ew, rowptr, rank, pair);

    // ---- per-node prep (LDS-aggregated histogram) + degree-sort permutation ----
    node_prep_k<<<g(N_NODES, B), B, 0, stream>>>(rowptr, pair, y, mask, xwt, dhist);
    bscan_k<<<1, 64, 0, stream>>>(dhist, bcur);
    perm_k<<<g(N_NODES, B), B, 0, stream>>>(rowptr, bcur, perm);

    // ---- project first: xwt[:, 0:40) = fp16(x @ W) ----
    xw_k<<<g((long long)N_NODES * CCH, B), B, 0, stream>>>(x, Wm, xwt);

    // ---- fused propagation: 3 CSR walks, degree-sorted node order ----
    fused1_k<<<g((long long)N_NODES * CH8, B), B, 0, stream>>>(
        rowptr, pair, perm, xwt, comb);
    fused2_k<<<g((long long)N_NODES * CH8, B), B, 0, stream>>>(
        rowptr, pair, perm, comb, bias, out, lBh);
    lpa3_k<<<g((long long)N_NODES * CH8, B), B, 0, stream>>>(
        rowptr, pair, perm, lBh, lpa_out);
}

// Round 17
// 239.928 us; speedup vs baseline: 1.9312x; 1.0658x over previous
//
#include <hip/hip_runtime.h>
#include <hip/hip_fp16.h>

constexpr int N_NODES     = 50000;
constexpr int N_EDGES     = 800000;
constexpr int IN_FEAT     = 96;
constexpr int NUM_CLASSES = 40;
constexpr int CCH = NUM_CLASSES / 4;          // 10 chunks (xw_k)
constexpr int CH8 = NUM_CLASSES / 8;          // 5 chunks of 8 values (walks)
constexpr int HS  = 64;                       // xwt row stride in halves (128 B line)
constexpr int CS  = 96;                       // comb row stride in halves (192 B)
constexpr int LS  = 64;                       // lB row stride in halves (128 B)
constexpr int SCAN_B = 1024;
constexpr int NSCAN = (N_NODES + SCAN_B - 1) / SCAN_B;  // 49 blocks

// ---- fp16 pack/unpack (8 values <-> uint4) ----
__device__ __forceinline__ void h8_to_f(const uint4& u, float4& lo, float4& hi) {
    float2 f0 = __half22float2(*reinterpret_cast<const __half2*>(&u.x));
    float2 f1 = __half22float2(*reinterpret_cast<const __half2*>(&u.y));
    float2 f2 = __half22float2(*reinterpret_cast<const __half2*>(&u.z));
    float2 f3 = __half22float2(*reinterpret_cast<const __half2*>(&u.w));
    lo = make_float4(f0.x, f0.y, f1.x, f1.y);
    hi = make_float4(f2.x, f2.y, f3.x, f3.y);
}
__device__ __forceinline__ uint4 f_to_h8(const float4& lo, const float4& hi) {
    uint4 u;
    *reinterpret_cast<__half2*>(&u.x) = __floats2half2_rn(lo.x, lo.y);
    *reinterpret_cast<__half2*>(&u.y) = __floats2half2_rn(lo.z, lo.w);
    *reinterpret_cast<__half2*>(&u.z) = __floats2half2_rn(hi.x, hi.y);
    *reinterpret_cast<__half2*>(&u.w) = __floats2half2_rn(hi.z, hi.w);
    return u;
}

// ---- pass A: per-edge in-bucket rank + bucket count; 8 edges/thread for ILP ----
__global__ void rank_k(const int* __restrict__ col, int* __restrict__ cnt,
                       int* __restrict__ rank) {
    int t = blockIdx.x * blockDim.x + threadIdx.x;
    if (t >= N_EDGES / 8) return;
    int4 c0 = reinterpret_cast<const int4*>(col)[2 * t];
    int4 c1 = reinterpret_cast<const int4*>(col)[2 * t + 1];
    int4 r0, r1;
    r0.x = atomicAdd(&cnt[c0.x], 1);
    r0.y = atomicAdd(&cnt[c0.y], 1);
    r0.z = atomicAdd(&cnt[c0.z], 1);
    r0.w = atomicAdd(&cnt[c0.w], 1);
    r1.x = atomicAdd(&cnt[c1.x], 1);
    r1.y = atomicAdd(&cnt[c1.y], 1);
    r1.z = atomicAdd(&cnt[c1.z], 1);
    r1.w = atomicAdd(&cnt[c1.w], 1);
    reinterpret_cast<int4*>(rank)[2 * t]     = r0;
    reinterpret_cast<int4*>(rank)[2 * t + 1] = r1;
}

// ---- 3-stage parallel exclusive scan of cnt[0..N_NODES) -> rowptr ----
__global__ __launch_bounds__(SCAN_B) void scan1_k(const int* __restrict__ cnt,
                                                  int* __restrict__ pscan,
                                                  int* __restrict__ bsum) {
    __shared__ int buf[SCAN_B];
    int tid = threadIdx.x;
    int i = blockIdx.x * SCAN_B + tid;
    int v = (i < N_NODES) ? cnt[i] : 0;
    buf[tid] = v;
    __syncthreads();
    for (int off = 1; off < SCAN_B; off <<= 1) {
        int t = (tid >= off) ? buf[tid - off] : 0;
        __syncthreads();
        buf[tid] += t;
        __syncthreads();
    }
    if (i < N_NODES) pscan[i] = buf[tid] - v;        // block-local exclusive
    if (tid == SCAN_B - 1) bsum[blockIdx.x] = buf[tid];
}

__global__ void scan2_k(const int* __restrict__ bsum, int* __restrict__ boff,
                        int* __restrict__ rowptr) {
    __shared__ int buf[64];
    int tid = threadIdx.x;                            // 64 threads
    int v = (tid < NSCAN) ? bsum[tid] : 0;
    buf[tid] = v;
    __syncthreads();
    for (int off = 1; off < 64; off <<= 1) {
        int t = (tid >= off) ? buf[tid - off] : 0;
        __syncthreads();
        buf[tid] += t;
        __syncthreads();
    }
    boff[tid] = buf[tid] - v;                         // exclusive block offsets
    if (tid == NSCAN - 1) rowptr[N_NODES] = buf[tid]; // total == N_EDGES
}

__global__ void scan3_k(const int* __restrict__ pscan, const int* __restrict__ boff,
                        int* __restrict__ rowptr) {
    int i = blockIdx.x * blockDim.x + threadIdx.x;
    if (i < N_NODES) rowptr[i] = boff[i >> 10] + pscan[i];
}

// ---- pass B: CSR fill, atomic-free; 4 edges/thread ----
__global__ void fill_k(const int* __restrict__ row, const int* __restrict__ col,
                       const float* __restrict__ ew, const int* __restrict__ rowptr,
                       const int* __restrict__ rank, int2* __restrict__ pair) {
    int t = blockIdx.x * blockDim.x + threadIdx.x;
    if (t >= N_EDGES / 4) return;
    int4   c = reinterpret_cast<const int4*>(col)[t];
    int4   r = reinterpret_cast<const int4*>(row)[t];
    int4   k = reinterpret_cast<const int4*>(rank)[t];
    float4 w = reinterpret_cast<const float4*>(ew)[t];
    pair[rowptr[c.x] + k.x] = make_int2(r.x, __float_as_int(w.x));
    pair[rowptr[c.y] + k.y] = make_int2(r.y, __float_as_int(w.y));
    pair[rowptr[c.z] + k.z] = make_int2(r.z, __float_as_int(w.z));
    pair[rowptr[c.w] + k.w] = make_int2(r.w, __float_as_int(w.w));
}

// ---- per-node: weighted degree -> dinv (table + xwt row); masked label in xwt ----
__global__ void node_prep_k(const int* __restrict__ rowptr, const int2* __restrict__ pair,
                            const int* __restrict__ y, const int* __restrict__ mask,
                            unsigned short* __restrict__ xwt, float* __restrict__ dinv) {
    int i = blockIdx.x * blockDim.x + threadIdx.x;
    if (i >= N_NODES) return;
    int p0 = rowptr[i], p1 = rowptr[i + 1];
    float d = 1.0f;                                   // self-loop weight
    for (int p = p0; p < p1; ++p) d += __int_as_float(pair[p].y);
    float dv = d > 0.0f ? rsqrtf(d) : 0.0f;
    dinv[i] = dv;
    unsigned short* rowp = xwt + (size_t)i * HS;
    *reinterpret_cast<int*>(rowp + 40)   = (mask[i] != 0) ? y[i] : -1;  // bytes 80-84
    *reinterpret_cast<float*>(rowp + 42) = dv;                          // bytes 84-88
}

// ---- xw = x @ W -> fp16 halves [0,40) of xwt rows ----
__global__ __launch_bounds__(256) void xw_k(const float* __restrict__ x,
                                            const float* __restrict__ Wm,
                                            unsigned short* __restrict__ xwt) {
    __shared__ float4 Ws[IN_FEAT * CCH];              // 96 x 10 float4 = 15 KiB
    int tid = threadIdx.x;
    for (int t = tid; t < IN_FEAT * CCH; t += 256)
        Ws[t] = reinterpret_cast<const float4*>(Wm)[t];
    __syncthreads();
    int idx = blockIdx.x * 256 + tid;
    if (idx >= N_NODES * CCH) return;                 // 500k
    int i = idx / CCH;
    int j = idx - i * CCH;                            // 4-col chunk
    const float4* xr = reinterpret_cast<const float4*>(x + i * IN_FEAT);  // 24 f4
    float4 acc = make_float4(0.f, 0.f, 0.f, 0.f);
#pragma unroll
    for (int f4 = 0; f4 < IN_FEAT / 4; ++f4) {
        float4 xv = xr[f4];
        float4 w0 = Ws[(4 * f4 + 0) * CCH + j];
        float4 w1 = Ws[(4 * f4 + 1) * CCH + j];
        float4 w2 = Ws[(4 * f4 + 2) * CCH + j];
        float4 w3 = Ws[(4 * f4 + 3) * CCH + j];
        acc.x = fmaf(xv.x, w0.x, fmaf(xv.y, w1.x, fmaf(xv.z, w2.x, fmaf(xv.w, w3.x, acc.x))));
        acc.y = fmaf(xv.x, w0.y, fmaf(xv.y, w1.y, fmaf(xv.z, w2.y, fmaf(xv.w, w3.y, acc.y))));
        acc.z = fmaf(xv.x, w0.z, fmaf(xv.y, w1.z, fmaf(xv.z, w2.z, fmaf(xv.w, w3.z, acc.z))));
        acc.w = fmaf(xv.x, w0.w, fmaf(xv.y, w1.w, fmaf(xv.z, w2.w, fmaf(xv.w, w3.w, acc.w))));
    }
    uint2 h;
    *reinterpret_cast<__half2*>(&h.x) = __floats2half2_rn(acc.x, acc.y);
    *reinterpret_cast<__half2*>(&h.y) = __floats2half2_rn(acc.z, acc.w);
    reinterpret_cast<uint2*>(xwt + (size_t)i * HS)[j] = h;
}

// ---- K1: fused SGC hop1 + LPA iter1; writes comb with [g1_j | lA_j] interleave ----
__global__ void fused1_k(const int* __restrict__ rowptr, const int2* __restrict__ pair,
                         const unsigned short* __restrict__ xwt,
                         unsigned short* __restrict__ comb) {
    int idx = blockIdx.x * blockDim.x + threadIdx.x;
    if (idx >= N_NODES * CH8) return;                 // 250k
    int i = idx / CH8;
    int j = idx - i * CH8;                            // 8-col chunk
    int p0 = rowptr[i], p1 = rowptr[i + 1];
    const unsigned short* irow = xwt + (size_t)i * HS;
    float dc = *reinterpret_cast<const float*>(irow + 42);
    float selfw = dc * dc;
    uint4 vh = *reinterpret_cast<const uint4*>(irow + j * 8);
    float4 v0, v1; h8_to_f(vh, v0, v1);
    float4 s0 = make_float4(selfw * v0.x, selfw * v0.y, selfw * v0.z, selfw * v0.w);
    float4 s1 = make_float4(selfw * v1.x, selfw * v1.y, selfw * v1.z, selfw * v1.w);
    float4 a0 = make_float4(0.f, 0.f, 0.f, 0.f);
    float4 a1 = make_float4(0.f, 0.f, 0.f, 0.f);
    int base = j << 3;
    for (int p = p0; p < p1; ++p) {
        int2 pr = pair[p];
        int s = pr.x;
        float w = __int_as_float(pr.y);
        const unsigned short* srow = xwt + (size_t)s * HS;
        uint4 uh = *reinterpret_cast<const uint4*>(srow + j * 8);
        int   t  = *reinterpret_cast<const int*>(srow + 40) - base;
        float ds = *reinterpret_cast<const float*>(srow + 42);
        float nv = ds * (w * dc);                     // gcn norm on the fly
        float4 u0, u1; h8_to_f(uh, u0, u1);
        s0.x = fmaf(nv, u0.x, s0.x); s0.y = fmaf(nv, u0.y, s0.y);
        s0.z = fmaf(nv, u0.z, s0.z); s0.w = fmaf(nv, u0.w, s0.w);
        s1.x = fmaf(nv, u1.x, s1.x); s1.y = fmaf(nv, u1.y, s1.y);
        s1.z = fmaf(nv, u1.z, s1.z); s1.w = fmaf(nv, u1.w, s1.w);
        a0.x += (t == 0) ? w : 0.f; a0.y += (t == 1) ? w : 0.f;
        a0.z += (t == 2) ? w : 0.f; a0.w += (t == 3) ? w : 0.f;
        a1.x += (t == 4) ? w : 0.f; a1.y += (t == 5) ? w : 0.f;
        a1.z += (t == 6) ? w : 0.f; a1.w += (t == 7) ? w : 0.f;
    }
    // interleaved: chunk j owns halves [16j, 16j+16): g1 first 8, lA next 8
    unsigned short* crow = comb + (size_t)i * CS + j * 16;
    *reinterpret_cast<uint4*>(crow)     = f_to_h8(s0, s1);   // g1_j (16 B)
    *reinterpret_cast<uint4*>(crow + 8) = f_to_h8(a0, a1);   // lA_j (16 B, same sector)
}

// ---- K2: fused SGC hop2 (+bias -> out f32) + LPA iter2; 1 sector/edge ----
__global__ void fused2_k(const int* __restrict__ rowptr, const int2* __restrict__ pair,
                         const float* __restrict__ dinv,
                         const unsigned short* __restrict__ comb,
                         const float* __restrict__ bias,
                         float* __restrict__ out, unsigned short* __restrict__ lBh) {
    int idx = blockIdx.x * blockDim.x + threadIdx.x;
    if (idx >= N_NODES * CH8) return;                 // 250k
    int i = idx / CH8;
    int j = idx - i * CH8;
    int p0 = rowptr[i], p1 = rowptr[i + 1];
    float dc = dinv[i];
    float selfw = dc * dc;
    const unsigned short* irow = comb + (size_t)i * CS + j * 16;
    uint4 vh = *reinterpret_cast<const uint4*>(irow);
    float4 v0, v1; h8_to_f(vh, v0, v1);
    float4 s0 = make_float4(selfw * v0.x, selfw * v0.y, selfw * v0.z, selfw * v0.w);
    float4 s1 = make_float4(selfw * v1.x, selfw * v1.y, selfw * v1.z, selfw * v1.w);
    float4 a0 = make_float4(0.f, 0.f, 0.f, 0.f);
    float4 a1 = make_float4(0.f, 0.f, 0.f, 0.f);
    for (int p = p0; p < p1; ++p) {
        int2 pr = pair[p];
        int s = pr.x;
        float w = __int_as_float(pr.y);
        float nv = dinv[s] * (w * dc);                // dinv: 200 KB L2-hot table
        const unsigned short* srow = comb + (size_t)s * CS + j * 16;
        uint4 uh = *reinterpret_cast<const uint4*>(srow);      // g1_j
        uint4 mh = *reinterpret_cast<const uint4*>(srow + 8);  // lA_j (same sector)
        float4 u0, u1; h8_to_f(uh, u0, u1);
        float4 m0, m1; h8_to_f(mh, m0, m1);
        s0.x = fmaf(nv, u0.x, s0.x); s0.y = fmaf(nv, u0.y, s0.y);
        s0.z = fmaf(nv, u0.z, s0.z); s0.w = fmaf(nv, u0.w, s0.w);
        s1.x = fmaf(nv, u1.x, s1.x); s1.y = fmaf(nv, u1.y, s1.y);
        s1.z = fmaf(nv, u1.z, s1.z); s1.w = fmaf(nv, u1.w, s1.w);
        a0.x = fmaf(w, m0.x, a0.x); a0.y = fmaf(w, m0.y, a0.y);
        a0.z = fmaf(w, m0.z, a0.z); a0.w = fmaf(w, m0.w, a0.w);
        a1.x = fmaf(w, m1.x, a1.x); a1.y = fmaf(w, m1.y, a1.y);
        a1.z = fmaf(w, m1.z, a1.z); a1.w = fmaf(w, m1.w, a1.w);
    }
    const float4* br = reinterpret_cast<const float4*>(bias) + 2 * j;
    float4 b0 = br[0], b1 = br[1];
    s0.x += b0.x; s0.y += b0.y; s0.z += b0.z; s0.w += b0.w;
    s1.x += b1.x; s1.y += b1.y; s1.z += b1.z; s1.w += b1.w;
    float4* oo = reinterpret_cast<float4*>(out + (size_t)i * NUM_CLASSES) + 2 * j;
    oo[0] = s0; oo[1] = s1;                           // final SGC output: f32
    *reinterpret_cast<uint4*>(lBh + (size_t)i * LS + j * 8) = f_to_h8(a0, a1);
}

// ---- K3: LPA iter3 (lBh -> lpa_out f32) ----
__global__ void lpa3_k(const int* __restrict__ rowptr, const int2* __restrict__ pair,
                       const unsigned short* __restrict__ lBh, float* __restrict__ lout) {
    int idx = blockIdx.x * blockDim.x + threadIdx.x;
    if (idx >= N_NODES * CH8) return;                 // 250k
    int i = idx / CH8;
    int j = idx - i * CH8;
    int p0 = rowptr[i], p1 = rowptr[i + 1];
    float4 a0 = make_float4(0.f, 0.f, 0.f, 0.f);
    float4 a1 = make_float4(0.f, 0.f, 0.f, 0.f);
    for (int p = p0; p < p1; ++p) {
        int2 pr = pair[p];
        int s = pr.x;
        float w = __int_as_float(pr.y);
        uint4 mh = *reinterpret_cast<const uint4*>(lBh + (size_t)s * LS + j * 8);
        float4 m0, m1; h8_to_f(mh, m0, m1);
        a0.x = fmaf(w, m0.x, a0.x); a0.y = fmaf(w, m0.y, a0.y);
        a0.z = fmaf(w, m0.z, a0.z); a0.w = fmaf(w, m0.w, a0.w);
        a1.x = fmaf(w, m1.x, a1.x); a1.y = fmaf(w, m1.y, a1.y);
        a1.z = fmaf(w, m1.z, a1.z); a1.w = fmaf(w, m1.w, a1.w);
    }
    float4* lo = reinterpret_cast<float4*>(lout + (size_t)i * NUM_CLASSES) + 2 * j;
    lo[0] = a0; lo[1] = a1;                           // final LPA output: f32
}

// ---------------- launch ----------------

extern "C" void kernel_launch(void* const* d_in, const int* in_sizes, int n_in,
                              void* d_out, int out_size, void* d_ws, size_t ws_size,
                              hipStream_t stream) {
    const float* x    = (const float*)d_in[0];
    const int*   ei   = (const int*)d_in[1];
    const int*   row  = ei;
    const int*   col  = ei + N_EDGES;
    const int*   y    = (const int*)d_in[2];
    const int*   mask = (const int*)d_in[3];
    const float* ew   = (const float*)d_in[4];
    const float* Wm   = (const float*)d_in[5];
    const float* bias = (const float*)d_in[6];
    float* out     = (float*)d_out;
    float* lpa_out = out + N_NODES * NUM_CLASSES;

    // workspace layout: big aligned tables first
    unsigned short* xwt  = (unsigned short*)d_ws;               // 50000*64 u16 = 6.4 MB
    unsigned short* comb = xwt + (size_t)N_NODES * HS;          // 50000*96 u16 = 9.6 MB
    unsigned short* lBh  = comb + (size_t)N_NODES * CS;         // 50000*64 u16 = 6.4 MB
    int2* pair  = (int2*)(lBh + (size_t)N_NODES * LS);          // 800000 int2 = 6.4 MB
    float* dinv = (float*)(pair + N_EDGES);                     // 50000
    int* wsi    = (int*)(dinv + 50000);
    int* cnt    = wsi;                                          // 50000
    int* pscan  = cnt + 50000;                                  // 50048
    int* bsum   = pscan + 50048;                                // 64
    int* boff   = bsum + 64;                                    // 64
    int* rowptr = boff + 64;                                    // 50004
    int* rank   = rowptr + 50004;                               // 800000

    const int B = 256;
    auto g = [](long long n, int b) { return (int)((n + b - 1) / b); };

    // ---- CSR build: rank pass (only atomic pass) -> scan -> atomic-free fill ----
    hipMemsetAsync(cnt, 0, 50000u * sizeof(int), stream);
    rank_k<<<g(N_EDGES / 8, B), B, 0, stream>>>(col, cnt, rank);
    scan1_k<<<NSCAN, SCAN_B, 0, stream>>>(cnt, pscan, bsum);
    scan2_k<<<1, 64, 0, stream>>>(bsum, boff, rowptr);
    scan3_k<<<g(N_NODES, B), B, 0, stream>>>(pscan, boff, rowptr);
    fill_k<<<g(N_EDGES / 4, B), B, 0, stream>>>(row, col, ew, rowptr, rank, pair);

    // ---- per-node prep: dinv table + (label, dinv) embedded in xwt rows ----
    node_prep_k<<<g(N_NODES, B), B, 0, stream>>>(rowptr, pair, y, mask, xwt, dinv);

    // ---- project first: xwt[:, 0:40) = fp16(x @ W) ----
    xw_k<<<g((long long)N_NODES * CCH, B), B, 0, stream>>>(x, Wm, xwt);

    // ---- fused propagation: 3 CSR walks, natural node order ----
    fused1_k<<<g((long long)N_NODES * CH8, B), B, 0, stream>>>(rowptr, pair, xwt, comb);
    fused2_k<<<g((long long)N_NODES * CH8, B), B, 0, stream>>>(rowptr, pair, dinv, comb,
                                                              bias, out, lBh);
    lpa3_k<<<g((long long)N_NODES * CH8, B), B, 0, stream>>>(rowptr, pair, lBh, lpa_out);
}